// Round 11
// baseline (176.933 us; speedup 1.0000x reference)
//
#include <hip/hip_runtime.h>
#include <math.h>

#define DIN 128
#define DH 256
#define DOUT 40

#define BSH 7                    // 128 nodes per bucket
#define BNODES 128
#define NBUK 391                 // ceil(50000/128)
#define CAP 4096                 // edge slots per bucket (mean ~2046, +8-pad worst ~3.2K)
#define PART_T 512
#define PART_EPB 8
#define PART_CHUNK (PART_T * PART_EPB)   // 4096 edges per block -> 196 blocks

typedef short short8 __attribute__((ext_vector_type(8)));
typedef float f32x4 __attribute__((ext_vector_type(4)));

// round-to-nearest-even float -> bf16 bits
__device__ inline unsigned f2bf(float f) {
    unsigned u = __float_as_uint(f);
    return (u + 0x7fffu + ((u >> 16) & 1u)) >> 16;
}
__device__ inline float bflo(unsigned u) { return __uint_as_float(u << 16); }
__device__ inline float bfhi(unsigned u) { return __uint_as_float(u & 0xffff0000u); }

// ------ partition + weight prep fused; gcur zeroed by memset (relative cursors) ---
__global__ __launch_bounds__(PART_T) void k_part_prep(
    const int* __restrict__ src, const int* __restrict__ dst,
    const float* __restrict__ W1, const float* __restrict__ W2,
    int* __restrict__ gcur, unsigned* __restrict__ raw,
    unsigned* __restrict__ w1t, unsigned* __restrict__ w2t, int E) {
    __shared__ int hist[NBUK];
    __shared__ int lbase[NBUK];
    int tid = threadIdx.x;

    // grid-stride weight prep (22.5K items over 100K threads: single pass)
    int prep_items = 256 * 64 + 48 * 128;
    for (int i = blockIdx.x * PART_T + tid; i < prep_items; i += gridDim.x * PART_T) {
        if (i < 256 * 64) {
            int c = i >> 6;
            int kk = (i & 63) * 2;
            w1t[i] = f2bf(W1[kk * DH + c]) | (f2bf(W1[(kk + 1) * DH + c]) << 16);
        } else {
            int j = i - 256 * 64;
            int col = j >> 7;
            int kk = (j & 127) * 2;
            float a = (col < DOUT) ? W2[kk * DOUT + col] : 0.f;
            float bb = (col < DOUT) ? W2[(kk + 1) * DOUT + col] : 0.f;
            w2t[j] = f2bf(a) | (f2bf(bb) << 16);
        }
    }

    int base_e = blockIdx.x * PART_CHUNK;
    for (int i = tid; i < NBUK; i += PART_T) hist[i] = 0;
    __syncthreads();

    int s[PART_EPB], d[PART_EPB];
#pragma unroll
    for (int k = 0; k < PART_EPB; ++k) {
        int e = base_e + k * PART_T + tid;
        if (e < E) { s[k] = src[e]; d[k] = dst[e]; }
        else d[k] = -1;
    }
#pragma unroll
    for (int k = 0; k < PART_EPB; ++k)
        if (d[k] >= 0) atomicAdd(&hist[d[k] >> BSH], 1);
    __syncthreads();

    for (int b = tid; b < NBUK; b += PART_T) {
        int c = hist[b];
        lbase[b] = b * CAP + (c ? atomicAdd(&gcur[b], c) : 0);  // gcur rel, memset-0
    }
    __syncthreads();
    for (int i = tid; i < NBUK; i += PART_T) hist[i] = 0;  // reuse as local cursor
    __syncthreads();

#pragma unroll
    for (int k = 0; k < PART_EPB; ++k) {
        if (d[k] >= 0) {
            int b = d[k] >> BSH;
            int pos = lbase[b] + atomicAdd(&hist[b], 1);
            if (pos < (b + 1) * CAP)
                raw[pos] = ((unsigned)(d[k] & (BNODES - 1)) << 16) | (unsigned)s[k];
        }
    }
}

// one block per bucket: count -> 8-padded scan -> row_ptr/row_end/dinv ->
// reorder into esrc; ALSO build pre-scaled xb'[g] = bf16(dinv[g] * x[g])
__global__ __launch_bounds__(256) void k_bucket_csr(
    const unsigned* __restrict__ raw, const int* __restrict__ gcur,
    const float* __restrict__ x,
    int* __restrict__ row_ptr, int* __restrict__ row_end,
    float* __restrict__ dinv, unsigned short* __restrict__ esrc,
    unsigned* __restrict__ xb, int n) {
    __shared__ int cnt[BNODES];
    __shared__ int scn[BNODES];
    __shared__ int lcur[BNODES];
    __shared__ float sdinv[BNODES];
    int b = blockIdx.x;
    int tid = threadIdx.x;
    int base = b * CAP;
    int size = gcur[b];              // relative count
    if (size > CAP) size = CAP;

    if (tid < BNODES) cnt[tid] = 0;
    __syncthreads();
    for (int i = tid; i < size; i += 256)
        atomicAdd(&cnt[raw[base + i] >> 16], 1);
    __syncthreads();

    if (tid < BNODES) scn[tid] = (cnt[tid] + 7) & ~7;
    __syncthreads();
    for (int off = 1; off < BNODES; off <<= 1) {
        int v = 0;
        if (tid < BNODES && tid >= off) v = scn[tid - off];
        __syncthreads();
        if (tid < BNODES) scn[tid] += v;
        __syncthreads();
    }
    if (tid < BNODES) {
        int c8 = (cnt[tid] + 7) & ~7;
        int excl = scn[tid] - c8;
        if (excl > CAP) excl = CAP;
        int re = excl + cnt[tid];
        if (re > CAP) re = CAP;
        lcur[tid] = excl;
        float dv = rsqrtf((float)cnt[tid] + 1.0f);
        sdinv[tid] = dv;
        int g = b * BNODES + tid;
        if (g < n) {
            row_ptr[g] = base + excl;
            row_end[g] = base + re;
            dinv[g]    = dv;
        }
    }
    __syncthreads();
    for (int i = tid; i < size; i += 256) {
        unsigned rec = raw[base + i];
        int pos = atomicAdd(&lcur[rec >> 16], 1);
        if (pos < CAP) esrc[base + pos] = (unsigned short)(rec & 0xffffu);
    }
    int nloc = n - b * BNODES;
    if (nloc > BNODES) nloc = BNODES;
    for (int i = tid; i < nloc * 64; i += 256) {
        int local = i >> 6, c = i & 63;
        int g = b * BNODES + local;
        float dv = sdinv[local];
        float2 v = ((const float2*)x)[(size_t)g * 64 + c];
        xb[(size_t)g * 64 + c] = f2bf(dv * v.x) | (f2bf(dv * v.y) << 16);
    }
}

// ---- FUSED: per-wave gather of its own 16 MFMA rows -> LDS -> MFMA MLP ---------
// 256 thr = 4 waves, 64 rows/block. Gather rows land in s_h[row][0..127] (dead
// until the h-overlay); A-frags read back wave-locally (no barrier). W1 B-frags
// read直接 from global (L2-resident). pb' = bf16(dinv[row] * (relu(.)@W2)).
__global__ __launch_bounds__(256) void k_agg_mlp(
    const uint2* __restrict__ xb2, const unsigned short* __restrict__ esrc,
    const int* __restrict__ row_ptr, const int* __restrict__ row_end,
    const float* __restrict__ dinv, const unsigned short* __restrict__ w1t,
    const float* __restrict__ b1, const unsigned short* __restrict__ w2t,
    unsigned short* __restrict__ pb, int n) {
    __shared__ __align__(16) unsigned short s_h[64][264];   // 33.8 KB
    __shared__ __align__(16) unsigned short s_w2[48][264];  // 25.3 KB
    const int tid = threadIdx.x;
    const int lane = tid & 63;
    const int wv = tid >> 6;
    const int l15 = lane & 15;
    const int lg = lane >> 4;
    const int hl = lane & 31;
    const int half = lane >> 5;
    const int blockRow = blockIdx.x * 64;

    // phase A: each wave gathers its 16 rows (8 node-pairs, half-wave per node)
    for (int p = 0; p < 8; ++p) {
        int rlocal = wv * 16 + p * 2 + half;
        int node = blockRow + rlocal;
        float ax = 0.f, ay = 0.f, az = 0.f, aw = 0.f;
        if (node < n) {
            int beg = row_ptr[node], end = row_end[node];
            uint2 sv = xb2[(size_t)node * 32 + hl];     // self term (pre-scaled)
            ax = bflo(sv.x); ay = bfhi(sv.x); az = bflo(sv.y); aw = bfhi(sv.y);
            int t = beg;
            for (; t + 8 <= end; t += 8) {
                uint4 q = *(const uint4*)(esrc + t);    // 8 edges, 8-aligned
                int s0 = q.x & 0xffff, s1 = q.x >> 16, s2 = q.y & 0xffff, s3 = q.y >> 16;
                int s4 = q.z & 0xffff, s5 = q.z >> 16, s6 = q.w & 0xffff, s7 = q.w >> 16;
                uint2 v0 = xb2[(size_t)s0 * 32 + hl], v1 = xb2[(size_t)s1 * 32 + hl];
                uint2 v2 = xb2[(size_t)s2 * 32 + hl], v3 = xb2[(size_t)s3 * 32 + hl];
                uint2 v4 = xb2[(size_t)s4 * 32 + hl], v5 = xb2[(size_t)s5 * 32 + hl];
                uint2 v6 = xb2[(size_t)s6 * 32 + hl], v7 = xb2[(size_t)s7 * 32 + hl];
                ax += bflo(v0.x) + bflo(v1.x) + bflo(v2.x) + bflo(v3.x)
                    + bflo(v4.x) + bflo(v5.x) + bflo(v6.x) + bflo(v7.x);
                ay += bfhi(v0.x) + bfhi(v1.x) + bfhi(v2.x) + bfhi(v3.x)
                    + bfhi(v4.x) + bfhi(v5.x) + bfhi(v6.x) + bfhi(v7.x);
                az += bflo(v0.y) + bflo(v1.y) + bflo(v2.y) + bflo(v3.y)
                    + bflo(v4.y) + bflo(v5.y) + bflo(v6.y) + bflo(v7.y);
                aw += bfhi(v0.y) + bfhi(v1.y) + bfhi(v2.y) + bfhi(v3.y)
                    + bfhi(v4.y) + bfhi(v5.y) + bfhi(v6.y) + bfhi(v7.y);
            }
            for (; t < end; ++t) {
                int s = esrc[t];
                uint2 v = xb2[(size_t)s * 32 + hl];
                ax += bflo(v.x); ay += bfhi(v.x);
                az += bflo(v.y); aw += bfhi(v.y);
            }
            float dn = dinv[node];
            ax *= dn; ay *= dn; az *= dn; aw *= dn;
        }
        *(uint2*)&s_h[rlocal][hl * 4] =
            make_uint2(f2bf(ax) | (f2bf(ay) << 16), f2bf(az) | (f2bf(aw) << 16));
    }

    // wave-local A-fragment readback (compiler inserts lgkmcnt; rows are wave-own)
    short8 aF[4];
#pragma unroll
    for (int ks = 0; ks < 4; ++ks)
        aF[ks] = *(const short8*)&s_h[wv * 16 + l15][ks * 32 + lg * 8];
    __syncthreads();   // everyone done reading gather rows before h-overlay

    // GEMM1: B-fragments straight from global w1t (128 KB, L2-resident)
    f32x4 acc[16];
#pragma unroll
    for (int nt = 0; nt < 16; ++nt) acc[nt] = (f32x4){0.f, 0.f, 0.f, 0.f};
#pragma unroll
    for (int ks = 0; ks < 4; ++ks) {
#pragma unroll
        for (int nt = 0; nt < 16; ++nt) {
            int j = nt * 16 + l15;
            short8 bF = *(const short8*)(w1t + (size_t)j * 128 + ks * 32 + lg * 8);
            acc[nt] = __builtin_amdgcn_mfma_f32_16x16x32_bf16(aF[ks], bF, acc[nt], 0, 0, 0);
        }
    }

    // h = relu(acc + b1) -> s_h overlay (wave-own rows)
#pragma unroll
    for (int nt = 0; nt < 16; ++nt) {
        int col = nt * 16 + l15;
        float bias = b1[col];
#pragma unroll
        for (int r = 0; r < 4; ++r) {
            int row = wv * 16 + lg * 4 + r;
            float v = fmaxf(acc[nt][r] + bias, 0.f);
            s_h[row][col] = (unsigned short)f2bf(v);
        }
    }
    // stage W2T -> LDS
    for (int i = tid; i < 48 * 32; i += 256) {
        int j = i >> 5, seg = i & 31;
        short8 v = *(const short8*)(w2t + j * 256 + seg * 8);
        *(short8*)&s_w2[j][seg * 8] = v;
    }
    __syncthreads();

    // GEMM2: 16 rows x 48 cols, K=256
    f32x4 acc2[3];
#pragma unroll
    for (int t = 0; t < 3; ++t) acc2[t] = (f32x4){0.f, 0.f, 0.f, 0.f};
#pragma unroll
    for (int ks = 0; ks < 8; ++ks) {
        int k = ks * 32 + lg * 8;
        short8 aH = *(const short8*)&s_h[wv * 16 + l15][k];
#pragma unroll
        for (int t = 0; t < 3; ++t) {
            short8 bF = *(const short8*)&s_w2[t * 16 + l15][k];
            acc2[t] = __builtin_amdgcn_mfma_f32_16x16x32_bf16(aH, bF, acc2[t], 0, 0, 0);
        }
    }
    float dnr[4];
#pragma unroll
    for (int r = 0; r < 4; ++r) {
        int row = blockRow + wv * 16 + lg * 4 + r;
        dnr[r] = (row < n) ? dinv[row] : 0.f;
    }
#pragma unroll
    for (int t = 0; t < 3; ++t) {
        int col = t * 16 + l15;
        if (col < DOUT) {
#pragma unroll
            for (int r = 0; r < 4; ++r) {
                int row = blockRow + wv * 16 + lg * 4 + r;
                if (row < n)
                    pb[(size_t)row * DOUT + col] = (unsigned short)f2bf(acc2[t][r] * dnr[r]);
            }
        }
    }
}

// -- layer 2 gather (pre-scaled bf16 p): 2 nodes/wave, pure sum, unroll-8 ---------
__global__ void k_gather2_lsm(const unsigned* __restrict__ pbu,
                              const unsigned short* __restrict__ esrc,
                              const int* __restrict__ row_ptr, const int* __restrict__ row_end,
                              const float* __restrict__ dinv, const float* __restrict__ b2,
                              float* __restrict__ out, int n) {
    int wid = (blockIdx.x * blockDim.x + threadIdx.x) >> 6;
    int lane = threadIdx.x & 63;
    int node = wid * 2 + (lane >> 5);
    int hl = lane & 31;
    if (node >= n) return;
    int beg = row_ptr[node], end = row_end[node];
    float dn = dinv[node];
    int cl = (hl < 20) ? hl : 0;
    unsigned pv = pbu[(size_t)node * 20 + cl];   // self term, pre-scaled
    float accx = bflo(pv);
    float accy = bfhi(pv);
    int t = beg;
    for (; t + 8 <= end; t += 8) {
        uint4 q = *(const uint4*)(esrc + t);
        int s0 = q.x & 0xffff, s1 = q.x >> 16, s2 = q.y & 0xffff, s3 = q.y >> 16;
        int s4 = q.z & 0xffff, s5 = q.z >> 16, s6 = q.w & 0xffff, s7 = q.w >> 16;
        unsigned p0 = pbu[(size_t)s0 * 20 + cl], p1 = pbu[(size_t)s1 * 20 + cl];
        unsigned p2 = pbu[(size_t)s2 * 20 + cl], p3 = pbu[(size_t)s3 * 20 + cl];
        unsigned p4 = pbu[(size_t)s4 * 20 + cl], p5 = pbu[(size_t)s5 * 20 + cl];
        unsigned p6 = pbu[(size_t)s6 * 20 + cl], p7 = pbu[(size_t)s7 * 20 + cl];
        accx += bflo(p0) + bflo(p1) + bflo(p2) + bflo(p3)
              + bflo(p4) + bflo(p5) + bflo(p6) + bflo(p7);
        accy += bfhi(p0) + bfhi(p1) + bfhi(p2) + bfhi(p3)
              + bfhi(p4) + bfhi(p5) + bfhi(p6) + bfhi(p7);
    }
    for (; t < end; ++t) {
        int s = esrc[t];
        unsigned p = pbu[(size_t)s * 20 + cl];
        accx += bflo(p);
        accy += bfhi(p);
    }
    float vx = -INFINITY, vy = -INFINITY;
    if (hl < 20) {
        float2 bv = ((const float2*)b2)[hl];
        vx = dn * accx + bv.x;
        vy = dn * accy + bv.y;
    }
    float m = fmaxf(vx, vy);
#pragma unroll
    for (int off = 16; off; off >>= 1) m = fmaxf(m, __shfl_xor(m, off, 32));
    float ex = (hl < 20) ? (expf(vx - m) + expf(vy - m)) : 0.f;
    float ssum = ex;
#pragma unroll
    for (int off = 16; off; off >>= 1) ssum += __shfl_xor(ssum, off, 32);
    float ls = logf(ssum);
    if (hl < 20)
        ((float2*)(out + (size_t)node * DOUT))[hl] = make_float2(vx - m - ls, vy - m - ls);
}

extern "C" void kernel_launch(void* const* d_in, const int* in_sizes, int n_in,
                              void* d_out, int out_size, void* d_ws, size_t ws_size,
                              hipStream_t stream) {
    const float* x  = (const float*)d_in[0];
    const int*   ei = (const int*)d_in[1];
    const float* W1 = (const float*)d_in[2];
    const float* b1 = (const float*)d_in[3];
    const float* W2 = (const float*)d_in[4];
    const float* b2 = (const float*)d_in[5];
    float* out = (float*)d_out;

    int n = in_sizes[0] / DIN;   // 50000
    int E = in_sizes[1] / 2;     // 800000
    const int* src = ei;
    const int* dst = ei + E;

    // workspace layout (~36 MB)
    int*            gcur    = (int*)d_ws;                          // 512 (NBUK used)
    int*            row_ptr = gcur + 512;                          // n
    int*            row_end = row_ptr + n;                         // n
    float*          dinv    = (float*)(row_end + n);               // n
    unsigned*       w1t     = (unsigned*)(dinv + n);               // 16384
    unsigned*       w2t     = w1t + 16384;                         // 6144
    unsigned*       raw     = w2t + 6144;                          // NBUK*CAP uint
    unsigned short* esrc    = (unsigned short*)(raw + (size_t)NBUK * CAP); // NBUK*CAP us
    unsigned*       xb      = (unsigned*)(esrc + (size_t)NBUK * CAP);      // n*64
    unsigned short* pb      = (unsigned short*)(xb + (size_t)n * 64);      // n*40 bf16

    const int B = 256;
    int part_blocks = (E + PART_CHUNK - 1) / PART_CHUNK;           // 196
    int npairs = (n + 1) / 2;                                      // 2 nodes per wave
    int gath_blocks = (int)(((size_t)npairs * 64 + B - 1) / B);

    hipMemsetAsync(gcur, 0, NBUK * sizeof(int), stream);
    k_part_prep<<<part_blocks, PART_T, 0, stream>>>(
        src, dst, W1, W2, gcur, raw, w1t, w2t, E);
    k_bucket_csr<<<NBUK, B, 0, stream>>>(raw, gcur, x, row_ptr, row_end, dinv, esrc, xb, n);
    k_agg_mlp<<<(n + 63) / 64, B, 0, stream>>>(
        (const uint2*)xb, esrc, row_ptr, row_end, dinv,
        (const unsigned short*)w1t, b1, (const unsigned short*)w2t, pb, n);
    k_gather2_lsm<<<gath_blocks, B, 0, stream>>>(
        (const unsigned*)pb, esrc, row_ptr, row_end, dinv, b2, out, n);
}

// Round 12
// 114.405 us; speedup vs baseline: 1.5466x; 1.5466x over previous
//
#include <hip/hip_runtime.h>
#include <math.h>

#define DIN 128
#define DH 256
#define DOUT 40
#define MLP_ROWS 64

#define BSH 7                    // 128 nodes per bucket
#define BNODES 128
#define NBUK 391                 // ceil(50000/128)
#define CAP 4096                 // edge slots per bucket (mean ~2046)
#define PART_T 512
#define PART_EPB 8
#define PART_CHUNK (PART_T * PART_EPB)   // 4096 edges per block

typedef short short8 __attribute__((ext_vector_type(8)));
typedef float f32x4 __attribute__((ext_vector_type(4)));

// round-to-nearest-even float -> bf16 bits
__device__ inline unsigned f2bf(float f) {
    unsigned u = __float_as_uint(f);
    return (u + 0x7fffu + ((u >> 16) & 1u)) >> 16;
}
__device__ inline float bflo(unsigned u) { return __uint_as_float(u << 16); }
__device__ inline float bfhi(unsigned u) { return __uint_as_float(u & 0xffff0000u); }

// -------------------- bucket-partition CSR build --------------------

// 196 blocks x 512 threads, 4096 edges/block: LDS histogram -> one global
// atomicAdd per (block,bucket) -> write packed {dstLow7<<16 | src16} records
__global__ __launch_bounds__(PART_T) void k_partition(
    const int* __restrict__ src, const int* __restrict__ dst,
    int* __restrict__ gcur, unsigned* __restrict__ raw, int E) {
    __shared__ int hist[NBUK];
    __shared__ int lbase[NBUK];
    int tid = threadIdx.x;
    int base_e = blockIdx.x * PART_CHUNK;

    for (int i = tid; i < NBUK; i += PART_T) hist[i] = 0;
    __syncthreads();

    int s[PART_EPB], d[PART_EPB];
#pragma unroll
    for (int k = 0; k < PART_EPB; ++k) {
        int e = base_e + k * PART_T + tid;
        if (e < E) { s[k] = src[e]; d[k] = dst[e]; }
        else d[k] = -1;
    }
#pragma unroll
    for (int k = 0; k < PART_EPB; ++k)
        if (d[k] >= 0) atomicAdd(&hist[d[k] >> BSH], 1);
    __syncthreads();

    for (int b = tid; b < NBUK; b += PART_T) {
        int c = hist[b];
        lbase[b] = c ? atomicAdd(&gcur[b], c) : 0;
    }
    __syncthreads();
    for (int i = tid; i < NBUK; i += PART_T) hist[i] = 0;  // reuse as local cursor
    __syncthreads();

#pragma unroll
    for (int k = 0; k < PART_EPB; ++k) {
        if (d[k] >= 0) {
            int b = d[k] >> BSH;
            int pos = lbase[b] + atomicAdd(&hist[b], 1);
            if (pos < (b + 1) * CAP)
                raw[pos] = ((unsigned)(d[k] & (BNODES - 1)) << 16) | (unsigned)s[k];
        }
    }
}

// one block per bucket: count(LDS) -> scan(LDS) -> row_ptr/row_end/dinv ->
// reorder records into dst-grouped esrc (ushort) within the bucket region
__global__ __launch_bounds__(256) void k_bucket_csr(
    const unsigned* __restrict__ raw, const int* __restrict__ gcur,
    int* __restrict__ row_ptr, int* __restrict__ row_end,
    float* __restrict__ dinv, unsigned short* __restrict__ esrc, int n) {
    __shared__ int cnt[BNODES];
    __shared__ int scn[BNODES];
    __shared__ int lcur[BNODES];
    int b = blockIdx.x;
    int tid = threadIdx.x;
    int base = b * CAP;
    int size = gcur[b] - base;
    if (size > CAP) size = CAP;

    if (tid < BNODES) cnt[tid] = 0;
    __syncthreads();
    for (int i = tid; i < size; i += 256)
        atomicAdd(&cnt[raw[base + i] >> 16], 1);
    __syncthreads();

    if (tid < BNODES) scn[tid] = cnt[tid];
    __syncthreads();
    for (int off = 1; off < BNODES; off <<= 1) {
        int v = 0;
        if (tid < BNODES && tid >= off) v = scn[tid - off];
        __syncthreads();
        if (tid < BNODES) scn[tid] += v;
        __syncthreads();
    }
    if (tid < BNODES) {
        int excl = scn[tid] - cnt[tid];
        lcur[tid] = excl;
        int g = b * BNODES + tid;
        if (g < n) {
            row_ptr[g] = base + excl;
            row_end[g] = base + excl + cnt[tid];
            dinv[g]    = rsqrtf((float)cnt[tid] + 1.0f);
        }
    }
    __syncthreads();
    for (int i = tid; i < size; i += 256) {
        unsigned rec = raw[base + i];
        int pos = atomicAdd(&lcur[rec >> 16], 1);
        esrc[base + pos] = (unsigned short)(rec & 0xffffu);
    }
}

// -------------------- merged prep: xb, w1t, w2t, gcur-init --------------------
__global__ void k_prep(const float* __restrict__ x, const float* __restrict__ W1,
                       const float* __restrict__ W2, unsigned* __restrict__ xb,
                       unsigned* __restrict__ w1t, unsigned* __restrict__ w2t,
                       int* __restrict__ gcur, int n64) {
    int i = blockIdx.x * blockDim.x + threadIdx.x;
    if (i < n64) {
        float2 v = ((const float2*)x)[i];
        xb[i] = f2bf(v.x) | (f2bf(v.y) << 16);
        return;
    }
    i -= n64;
    if (i < 256 * 64) {
        int c = i >> 6;
        int kk = (i & 63) * 2;
        w1t[i] = f2bf(W1[kk * DH + c]) | (f2bf(W1[(kk + 1) * DH + c]) << 16);
        return;
    }
    i -= 256 * 64;
    if (i < 48 * 128) {
        int col = i >> 7;
        int kk = (i & 127) * 2;
        float a = (col < DOUT) ? W2[kk * DOUT + col] : 0.f;
        float bb = (col < DOUT) ? W2[(kk + 1) * DOUT + col] : 0.f;
        w2t[i] = f2bf(a) | (f2bf(bb) << 16);
        return;
    }
    i -= 48 * 128;
    if (i < NBUK) gcur[i] = i * CAP;
}

// -------------------- layer 1 gather: 2 nodes/wave (32 lanes x 8B), unroll-8 ----
__global__ void k_gather_agg1(const uint2* __restrict__ xb2,
                              const unsigned short* __restrict__ esrc,
                              const int* __restrict__ row_ptr, const int* __restrict__ row_end,
                              const float* __restrict__ dinv, uint2* __restrict__ axb2, int n) {
    int wid = (blockIdx.x * blockDim.x + threadIdx.x) >> 6;
    int lane = threadIdx.x & 63;
    int node = wid * 2 + (lane >> 5);
    int hl = lane & 31;
    if (node >= n) return;
    int beg = row_ptr[node], end = row_end[node];
    float dn = dinv[node];
    uint2 sv = xb2[(size_t)node * 32 + hl];
    float ax = dn * bflo(sv.x), ay = dn * bfhi(sv.x);
    float az = dn * bflo(sv.y), aw = dn * bfhi(sv.y);
    int t = beg;
    for (; t + 8 <= end; t += 8) {
        int s0 = esrc[t],     s1 = esrc[t + 1], s2 = esrc[t + 2], s3 = esrc[t + 3];
        int s4 = esrc[t + 4], s5 = esrc[t + 5], s6 = esrc[t + 6], s7 = esrc[t + 7];
        float w0 = dinv[s0], w1 = dinv[s1], w2 = dinv[s2], w3 = dinv[s3];
        float w4 = dinv[s4], w5 = dinv[s5], w6 = dinv[s6], w7 = dinv[s7];
        uint2 v0 = xb2[(size_t)s0 * 32 + hl], v1 = xb2[(size_t)s1 * 32 + hl];
        uint2 v2 = xb2[(size_t)s2 * 32 + hl], v3 = xb2[(size_t)s3 * 32 + hl];
        uint2 v4 = xb2[(size_t)s4 * 32 + hl], v5 = xb2[(size_t)s5 * 32 + hl];
        uint2 v6 = xb2[(size_t)s6 * 32 + hl], v7 = xb2[(size_t)s7 * 32 + hl];
        ax += w0 * bflo(v0.x) + w1 * bflo(v1.x) + w2 * bflo(v2.x) + w3 * bflo(v3.x)
            + w4 * bflo(v4.x) + w5 * bflo(v5.x) + w6 * bflo(v6.x) + w7 * bflo(v7.x);
        ay += w0 * bfhi(v0.x) + w1 * bfhi(v1.x) + w2 * bfhi(v2.x) + w3 * bfhi(v3.x)
            + w4 * bfhi(v4.x) + w5 * bfhi(v5.x) + w6 * bfhi(v6.x) + w7 * bfhi(v7.x);
        az += w0 * bflo(v0.y) + w1 * bflo(v1.y) + w2 * bflo(v2.y) + w3 * bflo(v3.y)
            + w4 * bflo(v4.y) + w5 * bflo(v5.y) + w6 * bflo(v6.y) + w7 * bflo(v7.y);
        aw += w0 * bfhi(v0.y) + w1 * bfhi(v1.y) + w2 * bfhi(v2.y) + w3 * bfhi(v3.y)
            + w4 * bfhi(v4.y) + w5 * bfhi(v5.y) + w6 * bfhi(v6.y) + w7 * bfhi(v7.y);
    }
    for (; t + 4 <= end; t += 4) {
        int s0 = esrc[t], s1 = esrc[t + 1], s2 = esrc[t + 2], s3 = esrc[t + 3];
        float w0 = dinv[s0], w1 = dinv[s1], w2 = dinv[s2], w3 = dinv[s3];
        uint2 v0 = xb2[(size_t)s0 * 32 + hl];
        uint2 v1 = xb2[(size_t)s1 * 32 + hl];
        uint2 v2 = xb2[(size_t)s2 * 32 + hl];
        uint2 v3 = xb2[(size_t)s3 * 32 + hl];
        ax += w0 * bflo(v0.x) + w1 * bflo(v1.x) + w2 * bflo(v2.x) + w3 * bflo(v3.x);
        ay += w0 * bfhi(v0.x) + w1 * bfhi(v1.x) + w2 * bfhi(v2.x) + w3 * bfhi(v3.x);
        az += w0 * bflo(v0.y) + w1 * bflo(v1.y) + w2 * bflo(v2.y) + w3 * bflo(v3.y);
        aw += w0 * bfhi(v0.y) + w1 * bfhi(v1.y) + w2 * bfhi(v2.y) + w3 * bfhi(v3.y);
    }
    for (; t < end; ++t) {
        int s = esrc[t];
        float w = dinv[s];
        uint2 v = xb2[(size_t)s * 32 + hl];
        ax += w * bflo(v.x); ay += w * bfhi(v.x);
        az += w * bflo(v.y); aw += w * bfhi(v.y);
    }
    ax *= dn; ay *= dn; az *= dn; aw *= dn;
    axb2[(size_t)node * 32 + hl] =
        make_uint2(f2bf(ax) | (f2bf(ay) << 16), f2bf(az) | (f2bf(aw) << 16));
}

// -------------------- fused MFMA MLP: pb = bf16(relu(ax@W1+b1)@W2) -------------
__global__ __launch_bounds__(256) void k_mlp_mfma(
    const unsigned short* __restrict__ axb, const unsigned short* __restrict__ w1t,
    const float* __restrict__ b1, const unsigned short* __restrict__ w2t,
    unsigned short* __restrict__ pb, int n) {
    __shared__ __align__(16) char smem[65536];
    const int tid = threadIdx.x;
    const int lane = tid & 63;
    const int wv = tid >> 6;
    const int l15 = lane & 15;
    const int lg = lane >> 4;
    const int blockRow = blockIdx.x * MLP_ROWS;

    for (int i = tid; i < 256 * 16; i += 256) {
        int j = i >> 4, seg = i & 15;
        short8 v = *(const short8*)(w1t + j * 128 + seg * 8);
        *(short8*)(smem + j * 256 + ((seg * 16) ^ ((j & 7) << 4))) = v;
    }

    int arow = blockRow + wv * 16 + l15;
    if (arow >= n) arow = n - 1;
    const unsigned short* axp = axb + (size_t)arow * DIN + lg * 8;
    short8 aF[4];
#pragma unroll
    for (int ks = 0; ks < 4; ++ks) aF[ks] = *(const short8*)(axp + ks * 32);

    __syncthreads();

    f32x4 acc[16];
#pragma unroll
    for (int nt = 0; nt < 16; ++nt) acc[nt] = (f32x4){0.f, 0.f, 0.f, 0.f};
#pragma unroll
    for (int ks = 0; ks < 4; ++ks) {
        int kb = (ks * 32 + lg * 8) * 2;
#pragma unroll
        for (int nt = 0; nt < 16; ++nt) {
            int j = nt * 16 + l15;
            short8 bF = *(const short8*)(smem + j * 256 + (kb ^ ((j & 7) << 4)));
            acc[nt] = __builtin_amdgcn_mfma_f32_16x16x32_bf16(aF[ks], bF, acc[nt], 0, 0, 0);
        }
    }
    __syncthreads();

    unsigned short* s_h = (unsigned short*)smem;             // [64][264] bf16
    unsigned short* s_w2 = (unsigned short*)(smem + 33792);  // [48][264] bf16

#pragma unroll
    for (int nt = 0; nt < 16; ++nt) {
        int col = nt * 16 + l15;
        float bias = b1[col];
#pragma unroll
        for (int r = 0; r < 4; ++r) {
            int row = wv * 16 + lg * 4 + r;
            float v = fmaxf(acc[nt][r] + bias, 0.f);
            s_h[row * 264 + col] = (unsigned short)f2bf(v);
        }
    }
    for (int i = tid; i < 48 * 32; i += 256) {
        int j = i >> 5, seg = i & 31;
        short8 v = *(const short8*)(w2t + j * 256 + seg * 8);
        *(short8*)(s_w2 + j * 264 + seg * 8) = v;
    }
    __syncthreads();

    f32x4 acc2[3];
#pragma unroll
    for (int t = 0; t < 3; ++t) acc2[t] = (f32x4){0.f, 0.f, 0.f, 0.f};
#pragma unroll
    for (int ks = 0; ks < 8; ++ks) {
        int k = ks * 32 + lg * 8;
        short8 aH = *(const short8*)(s_h + (wv * 16 + l15) * 264 + k);
#pragma unroll
        for (int t = 0; t < 3; ++t) {
            short8 bF = *(const short8*)(s_w2 + (t * 16 + l15) * 264 + k);
            acc2[t] = __builtin_amdgcn_mfma_f32_16x16x32_bf16(aH, bF, acc2[t], 0, 0, 0);
        }
    }
#pragma unroll
    for (int t = 0; t < 3; ++t) {
        int col = t * 16 + l15;
        if (col < DOUT) {
#pragma unroll
            for (int r = 0; r < 4; ++r) {
                int row = blockRow + wv * 16 + lg * 4 + r;
                if (row < n) pb[(size_t)row * DOUT + col] = (unsigned short)f2bf(acc2[t][r]);
            }
        }
    }
}

// ---------- layer 2 gather (bf16 p): 2 nodes/wave, uint cols, unroll-8 ----------
__global__ void k_gather2_lsm(const unsigned* __restrict__ pbu,
                              const unsigned short* __restrict__ esrc,
                              const int* __restrict__ row_ptr, const int* __restrict__ row_end,
                              const float* __restrict__ dinv, const float* __restrict__ b2,
                              float* __restrict__ out, int n) {
    int wid = (blockIdx.x * blockDim.x + threadIdx.x) >> 6;
    int lane = threadIdx.x & 63;
    int node = wid * 2 + (lane >> 5);
    int hl = lane & 31;
    if (node >= n) return;
    int beg = row_ptr[node], end = row_end[node];
    float dn = dinv[node];
    int cl = (hl < 20) ? hl : 0;   // clamped uint column (2 bf16 cols per uint)
    unsigned pv = pbu[(size_t)node * 20 + cl];
    float accx = dn * bflo(pv);
    float accy = dn * bfhi(pv);
    int t = beg;
    for (; t + 8 <= end; t += 8) {
        int s0 = esrc[t],     s1 = esrc[t + 1], s2 = esrc[t + 2], s3 = esrc[t + 3];
        int s4 = esrc[t + 4], s5 = esrc[t + 5], s6 = esrc[t + 6], s7 = esrc[t + 7];
        float w0 = dinv[s0], w1 = dinv[s1], w2 = dinv[s2], w3 = dinv[s3];
        float w4 = dinv[s4], w5 = dinv[s5], w6 = dinv[s6], w7 = dinv[s7];
        unsigned p0 = pbu[(size_t)s0 * 20 + cl];
        unsigned p1 = pbu[(size_t)s1 * 20 + cl];
        unsigned p2 = pbu[(size_t)s2 * 20 + cl];
        unsigned p3 = pbu[(size_t)s3 * 20 + cl];
        unsigned p4 = pbu[(size_t)s4 * 20 + cl];
        unsigned p5 = pbu[(size_t)s5 * 20 + cl];
        unsigned p6 = pbu[(size_t)s6 * 20 + cl];
        unsigned p7 = pbu[(size_t)s7 * 20 + cl];
        accx += w0 * bflo(p0) + w1 * bflo(p1) + w2 * bflo(p2) + w3 * bflo(p3)
              + w4 * bflo(p4) + w5 * bflo(p5) + w6 * bflo(p6) + w7 * bflo(p7);
        accy += w0 * bfhi(p0) + w1 * bfhi(p1) + w2 * bfhi(p2) + w3 * bfhi(p3)
              + w4 * bfhi(p4) + w5 * bfhi(p5) + w6 * bfhi(p6) + w7 * bfhi(p7);
    }
    for (; t + 4 <= end; t += 4) {
        int s0 = esrc[t], s1 = esrc[t + 1], s2 = esrc[t + 2], s3 = esrc[t + 3];
        float w0 = dinv[s0], w1 = dinv[s1], w2 = dinv[s2], w3 = dinv[s3];
        unsigned p0 = pbu[(size_t)s0 * 20 + cl];
        unsigned p1 = pbu[(size_t)s1 * 20 + cl];
        unsigned p2 = pbu[(size_t)s2 * 20 + cl];
        unsigned p3 = pbu[(size_t)s3 * 20 + cl];
        accx += w0 * bflo(p0) + w1 * bflo(p1) + w2 * bflo(p2) + w3 * bflo(p3);
        accy += w0 * bfhi(p0) + w1 * bfhi(p1) + w2 * bfhi(p2) + w3 * bfhi(p3);
    }
    for (; t < end; ++t) {
        int s = esrc[t];
        float w = dinv[s];
        unsigned p = pbu[(size_t)s * 20 + cl];
        accx += w * bflo(p);
        accy += w * bfhi(p);
    }
    float vx = -INFINITY, vy = -INFINITY;
    if (hl < 20) {
        float2 bv = ((const float2*)b2)[hl];
        vx = dn * accx + bv.x;
        vy = dn * accy + bv.y;
    }
    float m = fmaxf(vx, vy);
#pragma unroll
    for (int off = 16; off; off >>= 1) m = fmaxf(m, __shfl_xor(m, off, 32));
    float ex = (hl < 20) ? (expf(vx - m) + expf(vy - m)) : 0.f;
    float ssum = ex;
#pragma unroll
    for (int off = 16; off; off >>= 1) ssum += __shfl_xor(ssum, off, 32);
    float ls = logf(ssum);
    if (hl < 20)
        ((float2*)(out + (size_t)node * DOUT))[hl] = make_float2(vx - m - ls, vy - m - ls);
}

extern "C" void kernel_launch(void* const* d_in, const int* in_sizes, int n_in,
                              void* d_out, int out_size, void* d_ws, size_t ws_size,
                              hipStream_t stream) {
    const float* x  = (const float*)d_in[0];
    const int*   ei = (const int*)d_in[1];
    const float* W1 = (const float*)d_in[2];
    const float* b1 = (const float*)d_in[3];
    const float* W2 = (const float*)d_in[4];
    const float* b2 = (const float*)d_in[5];
    float* out = (float*)d_out;

    int n = in_sizes[0] / DIN;   // 50000
    int E = in_sizes[1] / 2;     // 800000
    const int* src = ei;
    const int* dst = ei + E;

    // workspace layout (~36 MB)
    int*            gcur    = (int*)d_ws;                          // 512 (NBUK used)
    int*            row_ptr = gcur + 512;                          // n
    int*            row_end = row_ptr + n;                         // n
    float*          dinv    = (float*)(row_end + n);               // n
    unsigned*       w1t     = (unsigned*)(dinv + n);               // 16384
    unsigned*       w2t     = w1t + 16384;                         // 6144
    unsigned*       raw     = w2t + 6144;                          // NBUK*CAP uint
    unsigned short* esrc    = (unsigned short*)(raw + (size_t)NBUK * CAP); // NBUK*CAP us
    unsigned*       xb      = (unsigned*)(esrc + (size_t)NBUK * CAP);      // n*64
    unsigned*       axb     = xb + (size_t)n * 64;                 // n*64
    unsigned short* pb      = (unsigned short*)xb;                 // n*40 bf16, overlays dead xb

    const int B = 256;
    int part_blocks = (E + PART_CHUNK - 1) / PART_CHUNK;           // 196
    int prep_items = n * 64 + 256 * 64 + 48 * 128 + NBUK;
    int npairs = (n + 1) / 2;                                       // 2 nodes per wave
    int gath_blocks = (int)(((size_t)npairs * 64 + B - 1) / B);

    k_prep<<<(prep_items + B - 1) / B, B, 0, stream>>>(x, W1, W2, xb, w1t, w2t, gcur, n * 64);
    k_partition<<<part_blocks, PART_T, 0, stream>>>(src, dst, gcur, raw, E);
    k_bucket_csr<<<NBUK, B, 0, stream>>>(raw, gcur, row_ptr, row_end, dinv, esrc, n);
    k_gather_agg1<<<gath_blocks, B, 0, stream>>>(
        (const uint2*)xb, esrc, row_ptr, row_end, dinv, (uint2*)axb, n);
    k_mlp_mfma<<<(n + MLP_ROWS - 1) / MLP_ROWS, B, 0, stream>>>(
        (const unsigned short*)axb, (const unsigned short*)w1t, b1,
        (const unsigned short*)w2t, pb, n);
    k_gather2_lsm<<<gath_blocks, B, 0, stream>>>(
        (const unsigned*)pb, esrc, row_ptr, row_end, dinv, b2, out, n);
}